// Round 1
// baseline (127.228 us; speedup 1.0000x reference)
//
#include <hip/hip_runtime.h>
#include <hip/hip_bf16.h>
#include <math.h>

// Chamfer distance, fp32, N=M=16384, D=3.
// d2(i,j) = |a_i|^2 + |b_j|^2 - 2 a.b  (matches reference expansion).
// Track min_j (|b_j|^2 - 2 a.b) per row; add |a_i|^2 after the min.
// Publish block-partial mins via atomicMin on uint bits (values clamped >= 0).

constexpr int BLK = 256;   // threads per block
constexpr int U   = 4;     // A points per thread
constexpr int TM  = BLK * U;   // 1024 A points per block
constexpr int CH  = 1024;      // B chunk length per block (16 KB LDS as float4)

__global__ void init_min_kernel(unsigned* __restrict__ mins, int n) {
    int i = blockIdx.x * blockDim.x + threadIdx.x;
    if (i < n) mins[i] = 0x7F800000u;  // +inf bits
}

__global__ __launch_bounds__(BLK) void chamfer_pass_kernel(
    const float* __restrict__ P1, const float* __restrict__ P2,
    unsigned* __restrict__ min1, unsigned* __restrict__ min2,
    int n1, int n2)
{
    // blockIdx.z selects direction.
    const float* A; const float* B; unsigned* outMin; int nA; int nB;
    if (blockIdx.z == 0) { A = P1; B = P2; outMin = min1; nA = n1; nB = n2; }
    else                 { A = P2; B = P1; outMin = min2; nA = n2; nB = n1; }

    __shared__ float4 sB[CH];

    // Stage B chunk into LDS with |b|^2 in .w
    const int bstart = blockIdx.y * CH;
    for (int t = threadIdx.x; t < CH; t += BLK) {
        int j = bstart + t;
        if (j < nB) {
            float bx = B[3 * j + 0];
            float by = B[3 * j + 1];
            float bz = B[3 * j + 2];
            sB[t] = make_float4(bx, by, bz,
                                __builtin_fmaf(bz, bz, __builtin_fmaf(by, by, bx * bx)));
        } else {
            sB[t] = make_float4(0.f, 0.f, 0.f, __builtin_inff());  // never wins the min
        }
    }
    __syncthreads();

    const int abase = blockIdx.x * TM + threadIdx.x;
    float ax[U], ay[U], az[U], m[U];
    bool valid[U];
#pragma unroll
    for (int u = 0; u < U; ++u) {
        int i = abase + u * BLK;
        valid[u] = (i < nA);
        int ii = valid[u] ? i : 0;
        ax[u] = A[3 * ii + 0];
        ay[u] = A[3 * ii + 1];
        az[u] = A[3 * ii + 2];
        m[u] = 1e30f;
    }

    // Main loop: 5 VALU insts per (i,j) pair; one broadcast ds_read_b128 per j.
#pragma unroll 2
    for (int j = 0; j < CH; ++j) {
        float4 b = sB[j];
#pragma unroll
        for (int u = 0; u < U; ++u) {
            float dot = __builtin_fmaf(az[u], b.z,
                        __builtin_fmaf(ay[u], b.y, ax[u] * b.x));
            float p = __builtin_fmaf(-2.0f, dot, b.w);   // |b|^2 - 2 a.b
            m[u] = fminf(m[u], p);
        }
    }

#pragma unroll
    for (int u = 0; u < U; ++u) {
        if (valid[u]) {
            float sqa = __builtin_fmaf(az[u], az[u],
                        __builtin_fmaf(ay[u], ay[u], ax[u] * ax[u]));
            float v = fmaxf(m[u] + sqa, 0.0f);   // clamp tiny negatives (ref does too)
            atomicMin(&outMin[abase + u * BLK], __float_as_uint(v));
        }
    }
}

__global__ __launch_bounds__(1024) void reduce_sum_kernel(
    const unsigned* __restrict__ mins, int n, float* __restrict__ out)
{
    __shared__ float s[1024];
    float acc = 0.0f;
    for (int i = threadIdx.x; i < n; i += 1024) {
        float v = __uint_as_float(mins[i]);   // already >= 0
        acc += sqrtf(v);
    }
    s[threadIdx.x] = acc;
    __syncthreads();
    for (int w = 512; w > 0; w >>= 1) {
        if (threadIdx.x < w) s[threadIdx.x] += s[threadIdx.x + w];
        __syncthreads();
    }
    if (threadIdx.x == 0) out[0] = s[0];
}

extern "C" void kernel_launch(void* const* d_in, const int* in_sizes, int n_in,
                              void* d_out, int out_size, void* d_ws, size_t ws_size,
                              hipStream_t stream) {
    const float* P1 = (const float*)d_in[0];
    const float* P2 = (const float*)d_in[1];
    const int n1 = in_sizes[0] / 3;   // 16384
    const int n2 = in_sizes[1] / 3;   // 16384

    unsigned* min1 = (unsigned*)d_ws;
    unsigned* min2 = min1 + n1;
    float* out = (float*)d_out;

    // 1) init mins to +inf (d_ws is re-poisoned before every timed launch)
    {
        int n = n1 + n2;
        init_min_kernel<<<(n + 255) / 256, 256, 0, stream>>>(min1, n);
    }

    // 2) fused both-direction pass
    {
        int nmax = (n1 > n2) ? n1 : n2;
        dim3 grid((nmax + TM - 1) / TM, (nmax + CH - 1) / CH, 2);
        chamfer_pass_kernel<<<grid, BLK, 0, stream>>>(P1, P2, min1, min2, n1, n2);
    }

    // 3) sqrt + sum reduction into scalar
    reduce_sum_kernel<<<1, 1024, 0, stream>>>(min1, n1 + n2, out);
}

// Round 2
// 105.432 us; speedup vs baseline: 1.2067x; 1.2067x over previous
//
#include <hip/hip_runtime.h>
#include <hip/hip_bf16.h>
#include <math.h>

// Chamfer distance via MFMA, fp16 inputs / fp32 accumulate.
// K-packing trick: A_row = (-2ax,-2ay,-2az, 1, sqa, 0,0,0) (f16),
//                  B_col = ( bx,  by,  bz, sqb, 1, 0,0,0) (f16)
// => dot = sqa + sqb - 2 a.b = full squared distance.
// One v_mfma_f32_32x32x16_f16 yields a 32x32 tile of d^2; min over cols
// (per-lane running min, xor-shuffle reduce) gives min1 rows; min over rows
// (in-register tree + LDS atomicMin per col) gives min2. Both directions
// from ONE sweep over the 16384x16384 tile grid.
// All values (incl. norms) computed from QUANTIZED f16 coords -> d_hat is a
// true distance between quantized points; error ~1e-3/point << 65.6 threshold.

typedef _Float16 half8   __attribute__((ext_vector_type(8)));
typedef float    floatx16 __attribute__((ext_vector_type(16)));

constexpr int CH   = 2048;   // B points per block (LDS chunk)
constexpr int ROWS = 128;    // A rows per block = 4 waves * 32
constexpr int BLK  = 256;

__global__ __launch_bounds__(256) void init_kernel(unsigned* __restrict__ mins,
                                                   int n, float* __restrict__ out) {
    int i = blockIdx.x * blockDim.x + threadIdx.x;
    if (i < n) mins[i] = 0x7F800000u;   // +inf bits
    if (i == 0) out[0] = 0.0f;          // d_out is re-poisoned each launch
}

__device__ inline float tree16(const floatx16& d) {
    float a0 = fminf(d[0],  d[1]),  a1 = fminf(d[2],  d[3]);
    float a2 = fminf(d[4],  d[5]),  a3 = fminf(d[6],  d[7]);
    float a4 = fminf(d[8],  d[9]),  a5 = fminf(d[10], d[11]);
    float a6 = fminf(d[12], d[13]), a7 = fminf(d[14], d[15]);
    float b0 = fminf(a0, a1), b1 = fminf(a2, a3);
    float b2 = fminf(a4, a5), b3 = fminf(a6, a7);
    return fminf(fminf(b0, b1), fminf(b2, b3));
}

__global__ __launch_bounds__(BLK, 4) void chamfer_mfma_kernel(
    const float* __restrict__ P1, const float* __restrict__ P2,
    unsigned* __restrict__ min1, unsigned* __restrict__ min2,
    int n1, int n2)
{
    __shared__ uint2    sB[CH];        // per point: (f16x2(bx,by), f16x2(bz,sqb))
    __shared__ unsigned sColMin[CH];   // block-local col mins (uint bits)
    __shared__ float    sRowMin[ROWS];

    const int tid  = threadIdx.x;
    const int wave = tid >> 6;
    const int lane = tid & 63;
    const int n    = lane & 31;   // col / row-within-tile index
    const int g    = lane >> 5;   // K-half group: g=0 holds k=0..7, g=1 holds k=8..15 (zeros)
    const bool g0  = (g == 0);

    for (int i = tid; i < CH; i += BLK) sColMin[i] = 0x7F800000u;

    // ---- stage B chunk: quantize coords to f16, sqb from quantized coords ----
    const int bstart = blockIdx.y * CH;
    for (int i = tid; i < CH; i += BLK) {
        int j = bstart + i; if (j >= n2) j = n2 - 1;   // dup last point: harmless for min
        float bx = P2[3*j], by = P2[3*j+1], bz = P2[3*j+2];
        _Float16 hx = (_Float16)bx, hy = (_Float16)by, hz = (_Float16)bz;
        float qx = (float)hx, qy = (float)hy, qz = (float)hz;
        _Float16 hw = (_Float16)(qx*qx + qy*qy + qz*qz);
        union { _Float16 h[4]; uint2 u; } p;
        p.h[0] = hx; p.h[1] = hy; p.h[2] = hz; p.h[3] = hw;
        sB[i] = p.u;
    }

    // ---- A fragment (held all sweep): rows = blockIdx.x*128 + wave*32 + n ----
    int row = blockIdx.x * ROWS + wave * 32 + n;
    bool row_ok = (row < n1); if (!row_ok) row = n1 - 1;
    float ax = P1[3*row], ay = P1[3*row+1], az = P1[3*row+2];
    _Float16 hax = (_Float16)ax, hay = (_Float16)ay, haz = (_Float16)az;
    float qax = (float)hax, qay = (float)hay, qaz = (float)haz;
    _Float16 hsqa = (_Float16)(qax*qax + qay*qay + qaz*qaz);
    const _Float16 h0 = (_Float16)0.0f;
    half8 af;
    af[0] = g0 ? (_Float16)(-2.0f * qax) : h0;   // -2x exact (pow2 scale)
    af[1] = g0 ? (_Float16)(-2.0f * qay) : h0;
    af[2] = g0 ? (_Float16)(-2.0f * qaz) : h0;
    af[3] = g0 ? (_Float16)1.0f : h0;
    af[4] = g0 ? hsqa : h0;
    af[5] = h0; af[6] = h0; af[7] = h0;
    const _Float16 oneB = g0 ? (_Float16)1.0f : h0;

    __syncthreads();

    // ---- main sweep: 64 B-tiles, 2 per iteration ----
    floatx16 rowmin;
#pragma unroll
    for (int r = 0; r < 16; ++r) rowmin[r] = 1e30f;
    const floatx16 zacc = {};   // zero accumulator input

    for (int bt = 0; bt < CH / 32; bt += 2) {
        uint2 b0 = sB[bt * 32 + n];
        uint2 b1 = sB[bt * 32 + 32 + n];
        if (!g0) { b0.x = 0u; b0.y = 0u; b1.x = 0u; b1.y = 0u; }  // k=8..15 => zeros
        union { uint2 u; _Float16 h[4]; } u0, u1; u0.u = b0; u1.u = b1;
        half8 bf0, bf1;
        bf0[0]=u0.h[0]; bf0[1]=u0.h[1]; bf0[2]=u0.h[2]; bf0[3]=u0.h[3];
        bf0[4]=oneB;    bf0[5]=h0; bf0[6]=h0; bf0[7]=h0;
        bf1[0]=u1.h[0]; bf1[1]=u1.h[1]; bf1[2]=u1.h[2]; bf1[3]=u1.h[3];
        bf1[4]=oneB;    bf1[5]=h0; bf1[6]=h0; bf1[7]=h0;

        floatx16 d0 = __builtin_amdgcn_mfma_f32_32x32x16_f16(af, bf0, zacc, 0, 0, 0);
        floatx16 d1 = __builtin_amdgcn_mfma_f32_32x32x16_f16(af, bf1, zacc, 0, 0, 0);

        // min1: running per-row min (min3 fusion: rowmin = min3(rowmin, d0, d1))
#pragma unroll
        for (int r = 0; r < 16; ++r)
            rowmin[r] = fminf(rowmin[r], fminf(d0[r], d1[r]));

        // min2: per-tile min over the 16 rows each lane holds, then cross-group
        float t0 = tree16(d0);
        float t1 = tree16(d1);
        t0 = fminf(t0, __shfl_xor(t0, 32));
        t1 = fminf(t1, __shfl_xor(t1, 32));
        t0 = fmaxf(t0, 0.0f);
        t1 = fmaxf(t1, 0.0f);
        if (g0) {
            atomicMin(&sColMin[bt * 32 + n],      __float_as_uint(t0));
            atomicMin(&sColMin[bt * 32 + 32 + n], __float_as_uint(t1));
        }
    }

    // ---- min1: reduce across the 32 cols (lanes within group), publish ----
#pragma unroll
    for (int mask = 1; mask <= 16; mask <<= 1) {
#pragma unroll
        for (int r = 0; r < 16; ++r)
            rowmin[r] = fminf(rowmin[r], __shfl_xor(rowmin[r], mask));
    }
    if (n == 0) {
#pragma unroll
        for (int r = 0; r < 16; ++r) {
            int rr = wave * 32 + g * 4 + ((r & 3) + 8 * (r >> 2));  // C/D row map
            sRowMin[rr] = rowmin[r];
        }
    }
    __syncthreads();

    if (tid < ROWS) {
        int grow = blockIdx.x * ROWS + tid;
        if (grow < n1) {
            unsigned v = __float_as_uint(fmaxf(sRowMin[tid], 0.0f));
            unsigned cur = min1[grow];                 // read-check to skip atomics
            if (v < cur) atomicMin(&min1[grow], v);
        }
    }
    for (int i = tid; i < CH; i += BLK) {
        int j = bstart + i;
        if (j < n2) {
            unsigned v = sColMin[i];
            unsigned cur = min2[j];
            if (v < cur) atomicMin(&min2[j], v);
        }
    }
}

__global__ __launch_bounds__(256) void reduce_kernel(const unsigned* __restrict__ mins,
                                                     int ntot, float* __restrict__ out) {
    __shared__ float s[256];
    float acc = 0.0f;
    for (int i = blockIdx.x * 256 + threadIdx.x; i < ntot; i += gridDim.x * 256)
        acc += sqrtf(__uint_as_float(mins[i]));
    s[threadIdx.x] = acc;
    __syncthreads();
    for (int w = 128; w > 0; w >>= 1) {
        if (threadIdx.x < w) s[threadIdx.x] += s[threadIdx.x + w];
        __syncthreads();
    }
    if (threadIdx.x == 0) atomicAdd(out, s[0]);
}

extern "C" void kernel_launch(void* const* d_in, const int* in_sizes, int n_in,
                              void* d_out, int out_size, void* d_ws, size_t ws_size,
                              hipStream_t stream) {
    const float* P1 = (const float*)d_in[0];
    const float* P2 = (const float*)d_in[1];
    const int n1 = in_sizes[0] / 3;   // 16384
    const int n2 = in_sizes[1] / 3;   // 16384

    unsigned* min1 = (unsigned*)d_ws;
    unsigned* min2 = min1 + n1;
    float* out = (float*)d_out;

    {   // init mins to +inf and zero the output scalar
        int n = n1 + n2;
        init_kernel<<<(n + 255) / 256, 256, 0, stream>>>(min1, n, out);
    }
    {   // single dual-direction MFMA sweep
        dim3 grid((n1 + ROWS - 1) / ROWS, (n2 + CH - 1) / CH);
        chamfer_mfma_kernel<<<grid, BLK, 0, stream>>>(P1, P2, min1, min2, n1, n2);
    }
    {   // sqrt + sum, multi-block
        reduce_kernel<<<64, 256, 0, stream>>>(min1, n1 + n2, out);
    }
}

// Round 3
// 90.255 us; speedup vs baseline: 1.4097x; 1.1682x over previous
//
#include <hip/hip_runtime.h>
#include <hip/hip_bf16.h>
#include <math.h>

// Chamfer distance via MFMA, fp16 inputs / fp32 accumulate.
// K-packing: A_row = (-2ax,-2ay,-2az, 1, sqa, 0,0,0), B_col = (bx,by,bz, sqb, 1, 0,0,0)
// => MFMA dot = sqa + sqb - 2 a.b = full squared distance. One sweep serves BOTH
// chamfer directions: per-lane register rowmin (min over cols) + per-tile min tree
// over rows -> LDS atomicMin per column.
// R3 changes vs R2: g1-lane zero-K via LDS zero-slot address trick (no per-iter
// cndmask), both g-halves atomicMin same col addr (no shfl/branch in loop),
// 2 row-tiles per wave (2 MFMAs per B read), CH=1024 for 4 blocks/CU.

typedef _Float16 half8    __attribute__((ext_vector_type(8)));
typedef float    floatx16 __attribute__((ext_vector_type(16)));

constexpr int CH    = 1024;      // B points per block
constexpr int RT    = 2;         // row-tiles per wave
constexpr int WROWS = RT * 32;   // 64 rows per wave
constexpr int ROWS  = 4 * WROWS; // 256 rows per block (4 waves)
constexpr int BLK   = 256;

__global__ __launch_bounds__(256) void init_kernel(unsigned* __restrict__ mins,
                                                   int n, float* __restrict__ out) {
    int i = blockIdx.x * blockDim.x + threadIdx.x;
    if (i < n) mins[i] = 0x7F800000u;   // +inf bits
    if (i == 0) out[0] = 0.0f;
}

__global__ __launch_bounds__(BLK, 4) void chamfer_mfma_kernel(
    const float* __restrict__ P1, const float* __restrict__ P2,
    unsigned* __restrict__ min1, unsigned* __restrict__ min2,
    int n1, int n2)
{
    __shared__ uint2    sB[CH];
    __shared__ uint2    sZero;         // 8B of zeros for g1-lane B reads
    __shared__ unsigned sColMin[CH];
    __shared__ float    sRowMin[ROWS];

    const int tid  = threadIdx.x;
    const int wave = tid >> 6;
    const int lane = tid & 63;
    const int n    = lane & 31;
    const int g    = lane >> 5;
    const bool g0  = (g == 0);

    for (int i = tid; i < CH; i += BLK) sColMin[i] = 0x7F800000u;
    if (tid == 0) { sZero.x = 0u; sZero.y = 0u; }

    // ---- stage B chunk: f16-quantized coords + sqb (from quantized coords) ----
    const int bstart = blockIdx.y * CH;
    for (int i = tid; i < CH; i += BLK) {
        int j = bstart + i; if (j >= n2) j = n2 - 1;   // dup: harmless for min
        float bx = P2[3*j], by = P2[3*j+1], bz = P2[3*j+2];
        _Float16 hx = (_Float16)bx, hy = (_Float16)by, hz = (_Float16)bz;
        float qx = (float)hx, qy = (float)hy, qz = (float)hz;
        _Float16 hw = (_Float16)(qx*qx + qy*qy + qz*qz);
        union { _Float16 h[4]; uint2 u; } p;
        p.h[0] = hx; p.h[1] = hy; p.h[2] = hz; p.h[3] = hw;
        sB[i] = p.u;
    }

    // ---- A fragments: RT row-tiles per wave, held in registers all sweep ----
    const _Float16 h0 = (_Float16)0.0f;
    half8 af[RT];
#pragma unroll
    for (int t = 0; t < RT; ++t) {
        int row = blockIdx.x * ROWS + wave * WROWS + t * 32 + n;
        if (row >= n1) row = n1 - 1;
        float ax = P1[3*row], ay = P1[3*row+1], az = P1[3*row+2];
        _Float16 hax = (_Float16)ax, hay = (_Float16)ay, haz = (_Float16)az;
        float qx = (float)hax, qy = (float)hay, qz = (float)haz;
        _Float16 hs = (_Float16)(qx*qx + qy*qy + qz*qz);
        af[t][0] = g0 ? (_Float16)(-2.0f * qx) : h0;
        af[t][1] = g0 ? (_Float16)(-2.0f * qy) : h0;
        af[t][2] = g0 ? (_Float16)(-2.0f * qz) : h0;
        af[t][3] = g0 ? (_Float16)1.0f : h0;
        af[t][4] = g0 ? hs : h0;
        af[t][5] = h0; af[t][6] = h0; af[t][7] = h0;
    }
    unsigned c2;   // packed (oneB, 0): loop-invariant reg for bf[4..5]
    { union { _Float16 h[2]; unsigned u; } q;
      q.h[0] = g0 ? (_Float16)1.0f : h0; q.h[1] = h0; c2 = q.u; }

    __syncthreads();

    floatx16 rowmin[RT];
#pragma unroll
    for (int t = 0; t < RT; ++t)
#pragma unroll
        for (int r = 0; r < 16; ++r) rowmin[t][r] = 1e30f;
    const floatx16 zacc = {};

    // g0 lanes walk sB; g1 lanes pinned to the zero slot (k=8..15 contributes 0)
    const uint2* bp   = g0 ? (sB + n) : (&sZero);
    const int    step = g0 ? 32 : 0;

#pragma unroll 2
    for (int bt = 0; bt < CH / 32; ++bt) {
        uint2 b = *bp; bp += step;
        union { half8 v; unsigned u[4]; } bu;
        bu.u[0] = b.x; bu.u[1] = b.y; bu.u[2] = c2; bu.u[3] = 0u;

        floatx16 d0 = __builtin_amdgcn_mfma_f32_32x32x16_f16(af[0], bu.v, zacc, 0, 0, 0);
        floatx16 d1 = __builtin_amdgcn_mfma_f32_32x32x16_f16(af[1], bu.v, zacc, 0, 0, 0);

        // min1: per-lane running row mins
#pragma unroll
        for (int r = 0; r < 16; ++r) {
            rowmin[0][r] = fminf(rowmin[0][r], d0[r]);
            rowmin[1][r] = fminf(rowmin[1][r], d1[r]);
        }

        // min2: tree over the 32 rows this lane sees (both tiles), then atomic.
        // Both g-halves hit the same col addr: atomicMin merges (2-way, cheap).
        float m[8];
#pragma unroll
        for (int r = 0; r < 8; ++r)
            m[r] = fminf(fminf(d0[2*r], d1[2*r]), fminf(d0[2*r+1], d1[2*r+1]));
        float c0 = fminf(fminf(m[0], m[1]), fminf(m[2], m[3]));
        float c1 = fminf(fminf(m[4], m[5]), fminf(m[6], m[7]));
        float cm = fmaxf(fminf(c0, c1), 0.0f);
        atomicMin(&sColMin[bt * 32 + n], __float_as_uint(cm));
    }

    // ---- min1 epilogue: xor-shuffle reduce across the 32 cols per group ----
#pragma unroll
    for (int mask = 1; mask <= 16; mask <<= 1) {
#pragma unroll
        for (int t = 0; t < RT; ++t)
#pragma unroll
            for (int r = 0; r < 16; ++r)
                rowmin[t][r] = fminf(rowmin[t][r], __shfl_xor(rowmin[t][r], mask));
    }
    if (n == 0) {
#pragma unroll
        for (int t = 0; t < RT; ++t)
#pragma unroll
            for (int r = 0; r < 16; ++r) {
                int rr = wave * WROWS + t * 32 + g * 4 + ((r & 3) + 8 * (r >> 2));
                sRowMin[rr] = rowmin[t][r];
            }
    }
    __syncthreads();

    {   // flush row mins (ROWS == BLK)
        int grow = blockIdx.x * ROWS + tid;
        if (grow < n1) {
            unsigned v = __float_as_uint(fmaxf(sRowMin[tid], 0.0f));
            unsigned cur = min1[grow];
            if (v < cur) atomicMin(&min1[grow], v);
        }
    }
    for (int i = tid; i < CH; i += BLK) {   // flush col mins
        int j = bstart + i;
        if (j < n2) {
            unsigned v = sColMin[i];
            unsigned cur = min2[j];
            if (v < cur) atomicMin(&min2[j], v);
        }
    }
}

__global__ __launch_bounds__(256) void reduce_kernel(const unsigned* __restrict__ mins,
                                                     int ntot, float* __restrict__ out) {
    __shared__ float s[256];
    float acc = 0.0f;
    for (int i = blockIdx.x * 256 + threadIdx.x; i < ntot; i += gridDim.x * 256)
        acc += sqrtf(__uint_as_float(mins[i]));
    s[threadIdx.x] = acc;
    __syncthreads();
    for (int w = 128; w > 0; w >>= 1) {
        if (threadIdx.x < w) s[threadIdx.x] += s[threadIdx.x + w];
        __syncthreads();
    }
    if (threadIdx.x == 0) atomicAdd(out, s[0]);
}

extern "C" void kernel_launch(void* const* d_in, const int* in_sizes, int n_in,
                              void* d_out, int out_size, void* d_ws, size_t ws_size,
                              hipStream_t stream) {
    const float* P1 = (const float*)d_in[0];
    const float* P2 = (const float*)d_in[1];
    const int n1 = in_sizes[0] / 3;   // 16384
    const int n2 = in_sizes[1] / 3;   // 16384

    unsigned* min1 = (unsigned*)d_ws;
    unsigned* min2 = min1 + n1;
    float* out = (float*)d_out;

    {
        int n = n1 + n2;
        init_kernel<<<(n + 255) / 256, 256, 0, stream>>>(min1, n, out);
    }
    {
        dim3 grid((n1 + ROWS - 1) / ROWS, (n2 + CH - 1) / CH);
        chamfer_mfma_kernel<<<grid, BLK, 0, stream>>>(P1, P2, min1, min2, n1, n2);
    }
    reduce_kernel<<<64, 256, 0, stream>>>(min1, n1 + n2, out);
}

// Round 4
// 83.115 us; speedup vs baseline: 1.5307x; 1.0859x over previous
//
#include <hip/hip_runtime.h>
#include <hip/hip_bf16.h>
#include <math.h>

// Chamfer distance via MFMA, fp16 quantized / fp32 accumulate.
// K-packing: A_row = (-2ax,-2ay,-2az, 1, sqa, 0,0,0), B_col = (bx,by,bz, sqb, 1, ...)
// => MFMA dot = sqa + sqb - 2 a.b = full squared distance (from quantized coords).
// R4: two sweeps (z=0: min over P2 for each P1 row; z=1: swapped). Inner loop is
// PURE row-min accumulation: 2 B-tiles per row-tile per iter -> v_min3 fusion,
// no col tree, no atomics anywhere. A-fragment k>=8 lanes are zero, so B-fragment
// g1 content is don't-care (0 * finite = 0) -> no zeroing of B reads.
// Partial row-mins go to distinct ws slots per (dir, ychunk); two tiny reduce
// kernels (no init kernel, no atomicAdd) produce the scalar.

typedef _Float16 half8    __attribute__((ext_vector_type(8)));
typedef float    floatx16 __attribute__((ext_vector_type(16)));

constexpr int CH    = 2048;      // B points per block chunk
constexpr int RT    = 2;         // row-tiles per wave
constexpr int WROWS = RT * 32;   // 64 rows per wave
constexpr int ROWS  = 4 * WROWS; // 256 rows per block
constexpr int BLK   = 256;

__global__ __launch_bounds__(BLK, 4) void chamfer_sweep_kernel(
    const float* __restrict__ P1, const float* __restrict__ P2,
    float* __restrict__ part, int n1, int n2, int YC)
{
    __shared__ uint2 sB[CH];
    __shared__ float sRowMin[ROWS];

    const int dir  = blockIdx.z;
    const float* A = dir == 0 ? P1 : P2;
    const float* B = dir == 0 ? P2 : P1;
    const int nA   = dir == 0 ? n1 : n2;
    const int nB   = dir == 0 ? n2 : n1;
    float* pbase   = part + (dir == 0 ? 0 : (size_t)YC * n1);

    const int tid  = threadIdx.x;
    const int wave = tid >> 6;
    const int lane = tid & 63;
    const int n    = lane & 31;
    const int g    = lane >> 5;
    const bool g0  = (g == 0);

    // ---- stage B chunk: f16-quantized coords + sqb (from quantized coords) ----
    const int bstart = blockIdx.y * CH;
    for (int i = tid; i < CH; i += BLK) {
        int j = bstart + i; if (j >= nB) j = nB - 1;   // dup last point: min-safe
        float bx = B[3*j], by = B[3*j+1], bz = B[3*j+2];
        _Float16 hx = (_Float16)bx, hy = (_Float16)by, hz = (_Float16)bz;
        float qx = (float)hx, qy = (float)hy, qz = (float)hz;
        _Float16 hw = (_Float16)(qx*qx + qy*qy + qz*qz);
        union { _Float16 h[4]; uint2 u; } p;
        p.h[0] = hx; p.h[1] = hy; p.h[2] = hz; p.h[3] = hw;
        sB[i] = p.u;
    }

    // ---- A fragments (RT row-tiles per wave), zeros in k>=5 / all of g1 ----
    const _Float16 h0 = (_Float16)0.0f;
    half8 af[RT];
#pragma unroll
    for (int t = 0; t < RT; ++t) {
        int row = blockIdx.x * ROWS + wave * WROWS + t * 32 + n;
        if (row >= nA) row = nA - 1;
        float ax = A[3*row], ay = A[3*row+1], az = A[3*row+2];
        _Float16 hax = (_Float16)ax, hay = (_Float16)ay, haz = (_Float16)az;
        float qx = (float)hax, qy = (float)hay, qz = (float)haz;
        _Float16 hs = (_Float16)(qx*qx + qy*qy + qz*qz);
        af[t][0] = g0 ? (_Float16)(-2.0f * qx) : h0;
        af[t][1] = g0 ? (_Float16)(-2.0f * qy) : h0;
        af[t][2] = g0 ? (_Float16)(-2.0f * qz) : h0;
        af[t][3] = g0 ? (_Float16)1.0f : h0;
        af[t][4] = g0 ? hs : h0;
        af[t][5] = h0; af[t][6] = h0; af[t][7] = h0;
    }
    unsigned c2;   // packed (1.0h, 0h): B-fragment k=4..5 constant (g1 don't-care)
    { union { _Float16 h[2]; unsigned u; } q;
      q.h[0] = (_Float16)1.0f; q.h[1] = h0; c2 = q.u; }

    __syncthreads();

    floatx16 rowmin[RT];
#pragma unroll
    for (int t = 0; t < RT; ++t)
#pragma unroll
        for (int r = 0; r < 16; ++r) rowmin[t][r] = 1e30f;
    const floatx16 zacc = {};

    // ---- main sweep: 2 B-tiles (64 points) per iteration, 4 MFMAs, 32 min3 ----
#pragma unroll 2
    for (int bt = 0; bt < CH / 64; ++bt) {
        uint2 b0 = sB[bt * 64 + n];        // broadcast: g0/g1 read same addr
        uint2 b1 = sB[bt * 64 + 32 + n];
        union { half8 v; unsigned u[4]; } bu0, bu1;
        bu0.u[0] = b0.x; bu0.u[1] = b0.y; bu0.u[2] = c2; bu0.u[3] = 0u;
        bu1.u[0] = b1.x; bu1.u[1] = b1.y; bu1.u[2] = c2; bu1.u[3] = 0u;

        floatx16 d00 = __builtin_amdgcn_mfma_f32_32x32x16_f16(af[0], bu0.v, zacc, 0, 0, 0);
        floatx16 d01 = __builtin_amdgcn_mfma_f32_32x32x16_f16(af[0], bu1.v, zacc, 0, 0, 0);
        floatx16 d10 = __builtin_amdgcn_mfma_f32_32x32x16_f16(af[1], bu0.v, zacc, 0, 0, 0);
        floatx16 d11 = __builtin_amdgcn_mfma_f32_32x32x16_f16(af[1], bu1.v, zacc, 0, 0, 0);

#pragma unroll
        for (int r = 0; r < 16; ++r) {
            rowmin[0][r] = fminf(fminf(rowmin[0][r], d00[r]), d01[r]);  // v_min3
            rowmin[1][r] = fminf(fminf(rowmin[1][r], d10[r]), d11[r]);
        }
    }

    // ---- epilogue: reduce across the 32 cols (xor-shuffle within n-group) ----
#pragma unroll
    for (int mask = 1; mask <= 16; mask <<= 1) {
#pragma unroll
        for (int t = 0; t < RT; ++t)
#pragma unroll
            for (int r = 0; r < 16; ++r)
                rowmin[t][r] = fminf(rowmin[t][r], __shfl_xor(rowmin[t][r], mask));
    }
    if (n == 0) {
#pragma unroll
        for (int t = 0; t < RT; ++t)
#pragma unroll
            for (int r = 0; r < 16; ++r) {
                int rr = wave * WROWS + t * 32 + g * 4 + ((r & 3) + 8 * (r >> 2));
                sRowMin[rr] = rowmin[t][r];
            }
    }
    __syncthreads();

    {   // coalesced partial write: distinct slot per (dir, ychunk, row) — no atomics
        int grow = blockIdx.x * ROWS + tid;   // ROWS == BLK
        if (grow < nA) pbase[(size_t)blockIdx.y * nA + grow] = sRowMin[tid];
    }
}

// Stage 1: per-row min over YC partials -> sqrt -> per-block sum
__global__ __launch_bounds__(256) void reduce1_kernel(
    const float* __restrict__ part, float* __restrict__ bsum,
    int n1, int n2, int YC)
{
    __shared__ float s[256];
    int r = blockIdx.x * 256 + threadIdx.x;
    float acc = 0.0f;
    int ntot = n1 + n2;
    if (r < ntot) {
        const float* p; int row, nA;
        if (r < n1) { p = part;                       row = r;      nA = n1; }
        else        { p = part + (size_t)YC * n1;     row = r - n1; nA = n2; }
        float m = 1e30f;
        for (int y = 0; y < YC; ++y) m = fminf(m, p[(size_t)y * nA + row]);
        acc = sqrtf(fmaxf(m, 0.0f));
    }
    s[threadIdx.x] = acc;
    __syncthreads();
    for (int w = 128; w > 0; w >>= 1) {
        if (threadIdx.x < w) s[threadIdx.x] += s[threadIdx.x + w];
        __syncthreads();
    }
    if (threadIdx.x == 0) bsum[blockIdx.x] = s[0];
}

// Stage 2: sum the per-block sums -> out[0] (no init/atomic needed)
__global__ __launch_bounds__(256) void reduce2_kernel(
    const float* __restrict__ bsum, int nb, float* __restrict__ out)
{
    __shared__ float s[256];
    float acc = 0.0f;
    for (int i = threadIdx.x; i < nb; i += 256) acc += bsum[i];
    s[threadIdx.x] = acc;
    __syncthreads();
    for (int w = 128; w > 0; w >>= 1) {
        if (threadIdx.x < w) s[threadIdx.x] += s[threadIdx.x + w];
        __syncthreads();
    }
    if (threadIdx.x == 0) out[0] = s[0];
}

extern "C" void kernel_launch(void* const* d_in, const int* in_sizes, int n_in,
                              void* d_out, int out_size, void* d_ws, size_t ws_size,
                              hipStream_t stream) {
    const float* P1 = (const float*)d_in[0];
    const float* P2 = (const float*)d_in[1];
    const int n1 = in_sizes[0] / 3;   // 16384
    const int n2 = in_sizes[1] / 3;   // 16384
    const int nmax = (n1 > n2) ? n1 : n2;
    const int YC = (nmax + CH - 1) / CH;          // y-chunks (same grid both dirs)

    float* part = (float*)d_ws;                   // [YC*n1 + YC*n2] partial row-mins
    float* bsum = part + (size_t)YC * (n1 + n2);  // per-block sums
    float* out  = (float*)d_out;

    {   // two independent sweeps (z = direction), pure register row-mins
        dim3 grid((nmax + ROWS - 1) / ROWS, YC, 2);
        chamfer_sweep_kernel<<<grid, BLK, 0, stream>>>(P1, P2, part, n1, n2, YC);
    }
    int nb = (n1 + n2 + 255) / 256;
    reduce1_kernel<<<nb, 256, 0, stream>>>(part, bsum, n1, n2, YC);
    reduce2_kernel<<<1, 256, 0, stream>>>(bsum, nb, out);
}